// Round 2
// baseline (67.187 us; speedup 1.0000x reference)
//
#include <hip/hip_runtime.h>
#include <math.h>

// Problem constants (match reference): B=8, N=256, MAX_DIM=2, D=4
#define PB 8
#define PN 256
#define PD 4
#define PEPS 1e-8f

// Single-kernel design:
//   1 block x 1024 threads = 16 waves; wave w handles (dim = w>>3, b = w&7).
//   Each wave holds both 256-element projection arrays in registers
//   (4 elems/lane, element index idx = r*64 + lane) and bitonic-sorts them
//   with __shfl_xor (j<64) and in-lane register swaps (j>=64). Zero LDS
//   traffic and zero block barriers during the sort; one __syncthreads at
//   the end to fold 16 wave partials into the scalar output.
//
// Validity of sorting: Hungarian assignment on cost |a_i - b_j| over scalars
// attains its minimum by matching in sorted order; the reference consumes
// only the total cost. The [B:2B) half of the concat is the mirrored
// matching with identical cost -> factor 2.

__device__ __forceinline__ void cmpswap(float& lo, float& hi, bool up) {
    float mn = fminf(lo, hi);
    float mx = fmaxf(lo, hi);
    lo = up ? mn : mx;
    hi = up ? mx : mn;
}

__global__ __launch_bounds__(1024) void hung_kernel(
    const float* __restrict__ set1,   // [B, N, D] fp32
    const float* __restrict__ set2,   // [B, N, D] fp32
    float* __restrict__ out)          // [1] fp32
{
    const int tid  = threadIdx.x;       // 0..1023
    const int wave = tid >> 6;          // 0..15
    const int lane = tid & 63;          // 0..63
    const int dim  = wave >> 3;         // 0 or 1
    const int b    = wave & 7;          // 0..7
    const float fdim = (float)dim;

    // ---- load 4 points per lane from each set, compute masked projections ----
    float p[4];   // set1 projections, element idx = r*64 + lane
    float q[4];   // set2 projections
    const float4* s1v = (const float4*)(set1 + (size_t)b * PN * PD);
    const float4* s2v = (const float4*)(set2 + (size_t)b * PN * PD);
    #pragma unroll
    for (int r = 0; r < 4; ++r) {
        int n = r * 64 + lane;
        float4 e1 = s1v[n];
        float4 e2 = s2v[n];
        // set1 mask: stored float label == dim (labels exact 0.0/1.0)
        bool m1 = (e1.z == fdim);
        // set2 mask: argmax over cols 2..3, first-index tie-break
        int lab2 = (e2.w > e2.z) ? 1 : 0;
        bool m2 = (lab2 == dim);
        float mx1 = m1 ? e1.x : 0.0f, my1 = m1 ? e1.y : 0.0f;
        float mx2 = m2 ? e2.x : 0.0f, my2 = m2 ? e2.y : 0.0f;
        // projection: x + sqrt(y + eps)/2 (y zeroed by the ref's aliasing bug)
        p[r] = mx1 + sqrtf(my1 + PEPS) * 0.5f;
        q[r] = mx2 + sqrtf(my2 + PEPS) * 0.5f;
    }

    // ---- bitonic sort 256 elements per array, fully in-wave ----
    // idx = r*64 + lane; direction up = ((idx & k) == 0)
    #pragma unroll
    for (int k = 2; k <= 256; k <<= 1) {
        #pragma unroll
        for (int j = k >> 1; j > 0; j >>= 1) {
            if (j == 128) {
                // k == 256: pairs (r0,r2),(r1,r3), always ascending
                cmpswap(p[0], p[2], true);  cmpswap(p[1], p[3], true);
                cmpswap(q[0], q[2], true);  cmpswap(q[1], q[3], true);
            } else if (j == 64) {
                // pairs (r0,r1),(r2,r3); k=128: second pair descends
                bool up1 = (k == 256);
                cmpswap(p[0], p[1], true);  cmpswap(p[2], p[3], up1);
                cmpswap(q[0], q[1], true);  cmpswap(q[2], q[3], up1);
            } else {
                // cross-lane pass: partner lane = lane ^ j
                bool lower = ((lane & j) == 0);
                #pragma unroll
                for (int r = 0; r < 4; ++r) {
                    int idx = r * 64 + lane;
                    bool up = ((idx & k) == 0);
                    bool keepmin = (up == lower);
                    float po = __shfl_xor(p[r], j, 64);
                    float qo = __shfl_xor(q[r], j, 64);
                    float pmn = fminf(p[r], po), pmx = fmaxf(p[r], po);
                    float qmn = fminf(q[r], qo), qmx = fmaxf(q[r], qo);
                    p[r] = keepmin ? pmn : pmx;
                    q[r] = keepmin ? qmn : qmx;
                }
            }
        }
    }

    // ---- per-lane matched cost, wave reduction ----
    float v = 0.0f;
    #pragma unroll
    for (int r = 0; r < 4; ++r) v += fabsf(p[r] - q[r]);
    #pragma unroll
    for (int off = 32; off > 0; off >>= 1)
        v += __shfl_xor(v, off, 64);

    __shared__ float wsum[16];
    if (lane == 0) wsum[wave] = v;
    __syncthreads();
    if (tid == 0) {
        float s = 0.0f;
        #pragma unroll
        for (int i = 0; i < 16; ++i) s += wsum[i];
        // x2 for concat symmetry, /N for the per-row mean
        out[0] = s * (2.0f / (float)PN);
    }
}

extern "C" void kernel_launch(void* const* d_in, const int* in_sizes, int n_in,
                              void* d_out, int out_size, void* d_ws, size_t ws_size,
                              hipStream_t stream) {
    const float* set1 = (const float*)d_in[0];   // [B,N,D] fp32
    const float* set2 = (const float*)d_in[1];   // [B,N,D] fp32
    float* out = (float*)d_out;                  // 1 float

    hung_kernel<<<1, 1024, 0, stream>>>(set1, set2, out);
}

// Round 3
// 59.065 us; speedup vs baseline: 1.1375x; 1.1375x over previous
//
#include <hip/hip_runtime.h>
#include <math.h>

// Problem constants (match reference): B=8, N=256, MAX_DIM=2, D=4
#define PB 8
#define PN 256
#define PD 4
#define PEPS 1e-8f

// Kernel 1: 16 blocks x 64 threads. Block = one wave = one (dim, b) task.
// Each wave holds both 256-element projection arrays in registers with
// layout idx = lane*4 + r (4 contiguous elements per lane) and bitonic-
// sorts them. With this layout the j=1,2 passes are in-lane register
// compare-exchanges (15 of 36 passes); only j>=4 passes (21) need
// __shfl_xor with lane mask j>>2. No LDS, no __syncthreads.
//
// Validity: Hungarian assignment on |a_i - b_j| over scalars is minimized
// by sorted-order matching; the reference consumes only the total cost,
// and the [B:2B) concat half is the mirrored matching (factor 2).

__device__ __forceinline__ void cswap(float& a, float& b, bool up) {
    float mn = fminf(a, b);
    float mx = fmaxf(a, b);
    a = up ? mn : mx;
    b = up ? mx : mn;
}

// One cross-lane bitonic pass (shuffle mask m) applied to both arrays.
__device__ __forceinline__ void xpass(float (&p)[4], float (&q)[4],
                                      int m, bool keepmin) {
    #pragma unroll
    for (int r = 0; r < 4; ++r) {
        float po = __shfl_xor(p[r], m, 64);
        float qo = __shfl_xor(q[r], m, 64);
        float pmn = fminf(p[r], po), pmx = fmaxf(p[r], po);
        float qmn = fminf(q[r], qo), qmx = fmaxf(q[r], qo);
        p[r] = keepmin ? pmn : pmx;
        q[r] = keepmin ? qmn : qmx;
    }
}

// In-lane j=2 then j=1 passes, direction `up`, both arrays.
__device__ __forceinline__ void lpass(float (&p)[4], float (&q)[4], bool up) {
    cswap(p[0], p[2], up); cswap(p[1], p[3], up);
    cswap(q[0], q[2], up); cswap(q[1], q[3], up);
    cswap(p[0], p[1], up); cswap(p[2], p[3], up);
    cswap(q[0], q[1], up); cswap(q[2], q[3], up);
}

__global__ __launch_bounds__(64) void hung_partial_kernel(
    const float* __restrict__ set1,   // [B, N, D] fp32
    const float* __restrict__ set2,   // [B, N, D] fp32
    float* __restrict__ partial)      // [16] fp32
{
    const int blk  = blockIdx.x;      // 0..15
    const int dim  = blk >> 3;        // 0 or 1
    const int b    = blk & 7;         // 0..7
    const int lane = threadIdx.x;     // 0..63 (one wave)
    const float fdim = (float)dim;

    // ---- load 4 consecutive points per lane, compute masked projections ----
    float p[4];   // set1 projections, element idx = lane*4 + r
    float q[4];   // set2 projections
    const float4* s1v = (const float4*)(set1 + (size_t)b * PN * PD);
    const float4* s2v = (const float4*)(set2 + (size_t)b * PN * PD);
    #pragma unroll
    for (int r = 0; r < 4; ++r) {
        int n = lane * 4 + r;
        float4 e1 = s1v[n];
        float4 e2 = s2v[n];
        bool m1 = (e1.z == fdim);              // set1: float label == dim
        int lab2 = (e2.w > e2.z) ? 1 : 0;      // set2: argmax, first-idx ties
        bool m2 = (lab2 == dim);
        float mx1 = m1 ? e1.x : 0.0f, my1 = m1 ? e1.y : 0.0f;
        float mx2 = m2 ? e2.x : 0.0f, my2 = m2 ? e2.y : 0.0f;
        // projection x + sqrt(y+eps)/2 (y zeroed by the ref's aliasing)
        p[r] = mx1 + sqrtf(my1 + PEPS) * 0.5f;
        q[r] = mx2 + sqrtf(my2 + PEPS) * 0.5f;
    }

    // ---- bitonic sort 256 elems (idx = lane*4 + r), ascending ----
    // k = 2: j=1 in-lane; pair (0,1) up, (2,3) down
    cswap(p[0], p[1], true);  cswap(p[2], p[3], false);
    cswap(q[0], q[1], true);  cswap(q[2], q[3], false);
    // k = 4: j=2,1 in-lane; up = ((idx&4)==0) = ((lane&1)==0)
    lpass(p, q, (lane & 1) == 0);
    // k = 8 .. 256
    #pragma unroll
    for (int k = 8; k <= 256; k <<= 1) {
        // up = ((idx & k) == 0); idx bit log2(k) is lane bit log2(k)-2
        bool up = (k == 256) ? true : ((lane & (k >> 2)) == 0);
        #pragma unroll
        for (int m = k >> 3; m >= 1; m >>= 1) {   // j = k/2 .. 4, m = j>>2
            bool lower = ((lane & m) == 0);        // (idx & j) == 0
            xpass(p, q, m, up == lower);
        }
        lpass(p, q, up);                           // j = 2, 1
    }

    // ---- per-lane matched cost, wave reduction, one store ----
    float v = fabsf(p[0] - q[0]) + fabsf(p[1] - q[1])
            + fabsf(p[2] - q[2]) + fabsf(p[3] - q[3]);
    #pragma unroll
    for (int off = 32; off > 0; off >>= 1)
        v += __shfl_xor(v, off, 64);
    if (lane == 0) partial[blk] = v;
}

// Kernel 2: fold 16 partials into the scalar output.
// total = sum * 2 (concat symmetry) / N (mean over rows)
__global__ __launch_bounds__(64) void hung_final_kernel(
    const float* __restrict__ partial,
    float* __restrict__ out)
{
    if (threadIdx.x == 0) {
        float s = 0.0f;
        #pragma unroll
        for (int i = 0; i < 16; ++i) s += partial[i];
        out[0] = s * (2.0f / (float)PN);
    }
}

extern "C" void kernel_launch(void* const* d_in, const int* in_sizes, int n_in,
                              void* d_out, int out_size, void* d_ws, size_t ws_size,
                              hipStream_t stream) {
    const float* set1 = (const float*)d_in[0];   // [B,N,D] fp32
    const float* set2 = (const float*)d_in[1];   // [B,N,D] fp32
    float* partial = (float*)d_ws;               // 16 floats scratch
    float* out = (float*)d_out;                  // 1 float

    hung_partial_kernel<<<16, 64, 0, stream>>>(set1, set2, partial);
    hung_final_kernel<<<1, 64, 0, stream>>>(partial, out);
}